// Round 7
// baseline (429.740 us; speedup 1.0000x reference)
//
#include <hip/hip_runtime.h>
#include <math.h>

#define N_NODES  50000
#define N_EDGES  800000
#define FDIM     128
#define N_GRAPHS 500
#define NEG_SLOPE 0.2f
#define EN_TOTAL (N_EDGES + N_NODES)
#define SCAN_NB ((N_NODES + 255) / 256)   // 196
#define GEMM_TILES ((N_NODES + 31) / 32)  // 1563
#define GEMM_BLOCKS ((GEMM_TILES + 3) / 4)

typedef short bf16x8 __attribute__((ext_vector_type(8)));
typedef float f32x4 __attribute__((ext_vector_type(4)));

static __device__ __forceinline__ float lrelu(float x) {
    return x >= 0.f ? x : NEG_SLOPE * x;
}
static __device__ __forceinline__ unsigned short f2bf(float v) {
    unsigned int u = __float_as_uint(v);
    u += 0x7fffu + ((u >> 16) & 1u);
    return (unsigned short)(u >> 16);
}
static __device__ __forceinline__ float bf2f(unsigned short s) {
    return __uint_as_float(((unsigned int)s) << 16);
}

// ---------------- split X fp32 -> bf16 hi/lo planes ----------------
__global__ __launch_bounds__(256) void prep_planes(
    const float* __restrict__ X, unsigned short* __restrict__ hi,
    unsigned short* __restrict__ lo)
{
    const int total = N_NODES * FDIM / 4;
    for (int i = blockIdx.x * 256 + threadIdx.x; i < total; i += gridDim.x * 256) {
        const float4 v = ((const float4*)X)[i];
        ushort4 h4, l4;
        h4.x = f2bf(v.x); l4.x = f2bf(v.x - bf2f(h4.x));
        h4.y = f2bf(v.y); l4.y = f2bf(v.y - bf2f(h4.y));
        h4.z = f2bf(v.z); l4.z = f2bf(v.z - bf2f(h4.z));
        h4.w = f2bf(v.w); l4.w = f2bf(v.w - bf2f(h4.w));
        ((ushort4*)hi)[i] = h4;
        ((ushort4*)lo)[i] = l4;
    }
}

// ---------------- W (3 layers) -> transposed bf16 hi/lo planes [c][k] ----------
__global__ __launch_bounds__(256) void prep_wt(
    const float* __restrict__ W0, const float* __restrict__ W1,
    const float* __restrict__ W2, unsigned short* __restrict__ WT)
{
    const float* W = (blockIdx.x == 0) ? W0 : (blockIdx.x == 1) ? W1 : W2;
    unsigned short* hi = WT + (size_t)blockIdx.x * 2 * FDIM * FDIM;
    unsigned short* lo = hi + FDIM * FDIM;
    for (int i = threadIdx.x; i < FDIM * FDIM; i += 256) {
        const int k = i >> 7, c = i & 127;
        const float v = W[i];
        const unsigned short h = f2bf(v);
        hi[c * FDIM + k] = h;
        lo[c * FDIM + k] = f2bf(v - bf2f(h));
    }
}

// ---------------- h = X @ W via split-bf16 MFMA, no LDS ----------------
// Wave = 32-row tile x 128 cols. B-frags are contiguous bf16x8 loads from the
// precomputed W^T planes (64KB, L1/L2-hot), reused for both row-sub-tiles.
// 3-pass split: ah*bh + al*bh + ah*bl (fp32-accurate).
// Epilogue: bf16 Hb store + in-wave asrc/adst dots (verified D map: col=t*16+r16,
// row = 4*g + r).
__global__ __launch_bounds__(256) void gemm_mfma2(
    const unsigned short* __restrict__ Ahi, const unsigned short* __restrict__ Alo,
    const unsigned short* __restrict__ WThi, const unsigned short* __restrict__ WTlo,
    const float* __restrict__ Avs, const float* __restrict__ Avd,
    unsigned short* __restrict__ Hb, float* __restrict__ asrcN, float* __restrict__ adstN)
{
    const int tid = threadIdx.x, wv = tid >> 6, lane = tid & 63;
    const int r16 = lane & 15, g = lane >> 4;
    const int tile = blockIdx.x * 4 + wv;
    const int m0 = tile * 32;
    if (m0 >= N_NODES) return;

    const size_t ra0 = (size_t)min(m0 + r16,      N_NODES - 1) * FDIM;
    const size_t ra1 = (size_t)min(m0 + 16 + r16, N_NODES - 1) * FDIM;

    f32x4 acc0[8], acc1[8];
    #pragma unroll
    for (int t = 0; t < 8; ++t) {
        acc0[t] = (f32x4){0.f, 0.f, 0.f, 0.f};
        acc1[t] = (f32x4){0.f, 0.f, 0.f, 0.f};
    }

    #pragma unroll
    for (int cc = 0; cc < 4; ++cc) {
        const int k0 = cc * 32 + 8 * g;
        const bf16x8 ah0 = *(const bf16x8*)(Ahi + ra0 + k0);
        const bf16x8 al0 = *(const bf16x8*)(Alo + ra0 + k0);
        const bf16x8 ah1 = *(const bf16x8*)(Ahi + ra1 + k0);
        const bf16x8 al1 = *(const bf16x8*)(Alo + ra1 + k0);
        #pragma unroll
        for (int t = 0; t < 8; ++t) {
            const int c = t * 16 + r16;
            const bf16x8 bh = *(const bf16x8*)(WThi + c * FDIM + k0);
            const bf16x8 bl = *(const bf16x8*)(WTlo + c * FDIM + k0);
            acc0[t] = __builtin_amdgcn_mfma_f32_16x16x32_bf16(ah0, bh, acc0[t], 0, 0, 0);
            acc1[t] = __builtin_amdgcn_mfma_f32_16x16x32_bf16(ah1, bh, acc1[t], 0, 0, 0);
            acc0[t] = __builtin_amdgcn_mfma_f32_16x16x32_bf16(al0, bh, acc0[t], 0, 0, 0);
            acc1[t] = __builtin_amdgcn_mfma_f32_16x16x32_bf16(al1, bh, acc1[t], 0, 0, 0);
            acc0[t] = __builtin_amdgcn_mfma_f32_16x16x32_bf16(ah0, bl, acc0[t], 0, 0, 0);
            acc1[t] = __builtin_amdgcn_mfma_f32_16x16x32_bf16(ah1, bl, acc1[t], 0, 0, 0);
        }
    }

    float ps0[4] = {0,0,0,0}, pd0[4] = {0,0,0,0};
    float ps1[4] = {0,0,0,0}, pd1[4] = {0,0,0,0};
    const int row0b = m0 + 4 * g;
    const int row1b = m0 + 16 + 4 * g;
    #pragma unroll
    for (int t = 0; t < 8; ++t) {
        const float as_v = Avs[t * 16 + r16];
        const float ad_v = Avd[t * 16 + r16];
        #pragma unroll
        for (int r = 0; r < 4; ++r) {
            const float h0 = acc0[t][r];
            const float h1 = acc1[t][r];
            if (row0b + r < N_NODES)
                Hb[(size_t)(row0b + r) * FDIM + t * 16 + r16] = f2bf(h0);
            if (row1b + r < N_NODES)
                Hb[(size_t)(row1b + r) * FDIM + t * 16 + r16] = f2bf(h1);
            ps0[r] = fmaf(h0, as_v, ps0[r]); pd0[r] = fmaf(h0, ad_v, pd0[r]);
            ps1[r] = fmaf(h1, as_v, ps1[r]); pd1[r] = fmaf(h1, ad_v, pd1[r]);
        }
    }
    #pragma unroll
    for (int o = 1; o <= 8; o <<= 1) {
        #pragma unroll
        for (int r = 0; r < 4; ++r) {
            ps0[r] += __shfl_xor(ps0[r], o); pd0[r] += __shfl_xor(pd0[r], o);
            ps1[r] += __shfl_xor(ps1[r], o); pd1[r] += __shfl_xor(pd1[r], o);
        }
    }
    if (r16 == 0) {
        #pragma unroll
        for (int r = 0; r < 4; ++r) {
            if (row0b + r < N_NODES) { asrcN[row0b + r] = ps0[r]; adstN[row0b + r] = pd0[r]; }
            if (row1b + r < N_NODES) { asrcN[row1b + r] = ps1[r]; adstN[row1b + r] = pd1[r]; }
        }
    }
}

// ---------------- CSR build ----------------
__global__ void count_edges(const int* __restrict__ ei, int* __restrict__ cnt) {
    int i = blockIdx.x * 256 + threadIdx.x;
    if (i < EN_TOTAL) {
        int d = (i < N_EDGES) ? ei[N_EDGES + i] : (i - N_EDGES);
        atomicAdd(&cnt[d], 1);
    }
}

__global__ __launch_bounds__(256) void scan_block(const int* __restrict__ cnt,
                                                  int* __restrict__ off,
                                                  int* __restrict__ blockSums) {
    __shared__ int s[256];
    const int i = blockIdx.x * 256 + threadIdx.x;
    s[threadIdx.x] = (i < N_NODES) ? cnt[i] : 0;
    __syncthreads();
    #pragma unroll
    for (int d = 1; d < 256; d <<= 1) {
        int t = (threadIdx.x >= d) ? s[threadIdx.x - d] : 0;
        __syncthreads();
        s[threadIdx.x] += t;
        __syncthreads();
    }
    if (i < N_NODES) off[i + 1] = s[threadIdx.x];
    if (threadIdx.x == 255) blockSums[blockIdx.x] = s[255];
}

__global__ __launch_bounds__(256) void scan_sums(int* __restrict__ blockSums) {
    __shared__ int s[256];
    s[threadIdx.x] = (threadIdx.x < SCAN_NB) ? blockSums[threadIdx.x] : 0;
    __syncthreads();
    #pragma unroll
    for (int d = 1; d < 256; d <<= 1) {
        int t = (threadIdx.x >= d) ? s[threadIdx.x - d] : 0;
        __syncthreads();
        s[threadIdx.x] += t;
        __syncthreads();
    }
    if (threadIdx.x < SCAN_NB)
        blockSums[threadIdx.x] = (threadIdx.x == 0) ? 0 : s[threadIdx.x - 1];
}

__global__ __launch_bounds__(256) void add_base(int* __restrict__ off,
                                                const int* __restrict__ blockSums) {
    const int i = blockIdx.x * 256 + threadIdx.x;
    if (i < N_NODES) off[i + 1] += blockSums[blockIdx.x];
    if (i == 0) off[0] = 0;
}

__global__ void scatter_edges(const int* __restrict__ ei, const int* __restrict__ off,
                              int* __restrict__ cur, int* __restrict__ srcs) {
    int i = blockIdx.x * 256 + threadIdx.x;
    if (i < EN_TOTAL) {
        int s, d;
        if (i < N_EDGES) { s = ei[i]; d = ei[N_EDGES + i]; }
        else             { s = d = i - N_EDGES; }
        int p = off[d] + atomicAdd(&cur[d], 1);
        srcs[p] = s;
    }
}

// ---------------- segment softmax + weighted aggregation (bf16 H gather) -------
// One wave per dst node; 8 edge-groups x 8 feature-lanes; edge loop unrolled x2
// (4 outstanding 16B gathers per lane).
__global__ __launch_bounds__(256) void gat_aggregate(
    const unsigned short* __restrict__ Hb, const int* __restrict__ off,
    const int* __restrict__ srcs,
    const float* __restrict__ asrcN, const float* __restrict__ adstN,
    const float* __restrict__ bias,
    unsigned short* __restrict__ PHI, unsigned short* __restrict__ PLO,
    float* __restrict__ OUTF, int mode)
{
    const int wave = threadIdx.x >> 6, lane = threadIdx.x & 63;
    const int grp = lane >> 3, fl = lane & 7;

    for (int n = blockIdx.x * 4 + wave; n < N_NODES; n += gridDim.x * 4) {
        const int s0 = off[n], s1 = off[n + 1];
        const int deg = s1 - s0;
        const float ad = adstN[n];

        float e_reg = -1e30f;
        float m = -1e30f;
        for (int j = s0 + lane; j < s1; j += 64) {
            float e = lrelu(asrcN[srcs[j]] + ad);
            if (j - s0 < 64) e_reg = e;
            m = fmaxf(m, e);
        }
        #pragma unroll
        for (int o = 32; o; o >>= 1) m = fmaxf(m, __shfl_xor(m, o));

        float4 a0 = {0,0,0,0}, a1 = {0,0,0,0}, a2 = {0,0,0,0}, a3 = {0,0,0,0};
        float dn = 0.f;
        const unsigned short* Hf = Hb + (size_t)fl * 16;

        int j = s0 + grp;
        for (; j + 8 < s1; j += 16) {
            const int sA = srcs[j], sB = srcs[j + 8];
            const uint4* hpA = (const uint4*)(Hf + (size_t)sA * FDIM);
            const uint4* hpB = (const uint4*)(Hf + (size_t)sB * FDIM);
            const uint4 uA0 = hpA[0], uA1 = hpA[1];
            const uint4 uB0 = hpB[0], uB1 = hpB[1];
            const float exA = (deg <= 64) ? __expf(__shfl(e_reg, j - s0) - m)
                                          : __expf(lrelu(asrcN[sA] + ad) - m);
            const float exB = (deg <= 64) ? __expf(__shfl(e_reg, j + 8 - s0) - m)
                                          : __expf(lrelu(asrcN[sB] + ad) - m);
            dn += exA + exB;
            a0.x += exA * __uint_as_float(uA0.x << 16);
            a0.y += exA * __uint_as_float(uA0.x & 0xffff0000u);
            a0.z += exA * __uint_as_float(uA0.y << 16);
            a0.w += exA * __uint_as_float(uA0.y & 0xffff0000u);
            a1.x += exA * __uint_as_float(uA0.z << 16);
            a1.y += exA * __uint_as_float(uA0.z & 0xffff0000u);
            a1.z += exA * __uint_as_float(uA0.w << 16);
            a1.w += exA * __uint_as_float(uA0.w & 0xffff0000u);
            a2.x += exA * __uint_as_float(uA1.x << 16);
            a2.y += exA * __uint_as_float(uA1.x & 0xffff0000u);
            a2.z += exA * __uint_as_float(uA1.y << 16);
            a2.w += exA * __uint_as_float(uA1.y & 0xffff0000u);
            a3.x += exA * __uint_as_float(uA1.z << 16);
            a3.y += exA * __uint_as_float(uA1.z & 0xffff0000u);
            a3.z += exA * __uint_as_float(uA1.w << 16);
            a3.w += exA * __uint_as_float(uA1.w & 0xffff0000u);
            a0.x += exB * __uint_as_float(uB0.x << 16);
            a0.y += exB * __uint_as_float(uB0.x & 0xffff0000u);
            a0.z += exB * __uint_as_float(uB0.y << 16);
            a0.w += exB * __uint_as_float(uB0.y & 0xffff0000u);
            a1.x += exB * __uint_as_float(uB0.z << 16);
            a1.y += exB * __uint_as_float(uB0.z & 0xffff0000u);
            a1.z += exB * __uint_as_float(uB0.w << 16);
            a1.w += exB * __uint_as_float(uB0.w & 0xffff0000u);
            a2.x += exB * __uint_as_float(uB1.x << 16);
            a2.y += exB * __uint_as_float(uB1.x & 0xffff0000u);
            a2.z += exB * __uint_as_float(uB1.y << 16);
            a2.w += exB * __uint_as_float(uB1.y & 0xffff0000u);
            a3.x += exB * __uint_as_float(uB1.z << 16);
            a3.y += exB * __uint_as_float(uB1.z & 0xffff0000u);
            a3.z += exB * __uint_as_float(uB1.w << 16);
            a3.w += exB * __uint_as_float(uB1.w & 0xffff0000u);
        }
        if (j < s1) {
            const int s = srcs[j];
            const uint4* hp = (const uint4*)(Hf + (size_t)s * FDIM);
            const uint4 u0 = hp[0], u1 = hp[1];
            const float ex = (deg <= 64) ? __expf(__shfl(e_reg, j - s0) - m)
                                         : __expf(lrelu(asrcN[s] + ad) - m);
            dn += ex;
            a0.x += ex * __uint_as_float(u0.x << 16);
            a0.y += ex * __uint_as_float(u0.x & 0xffff0000u);
            a0.z += ex * __uint_as_float(u0.y << 16);
            a0.w += ex * __uint_as_float(u0.y & 0xffff0000u);
            a1.x += ex * __uint_as_float(u0.z << 16);
            a1.y += ex * __uint_as_float(u0.z & 0xffff0000u);
            a1.z += ex * __uint_as_float(u0.w << 16);
            a1.w += ex * __uint_as_float(u0.w & 0xffff0000u);
            a2.x += ex * __uint_as_float(u1.x << 16);
            a2.y += ex * __uint_as_float(u1.x & 0xffff0000u);
            a2.z += ex * __uint_as_float(u1.y << 16);
            a2.w += ex * __uint_as_float(u1.y & 0xffff0000u);
            a3.x += ex * __uint_as_float(u1.z << 16);
            a3.y += ex * __uint_as_float(u1.z & 0xffff0000u);
            a3.z += ex * __uint_as_float(u1.w << 16);
            a3.w += ex * __uint_as_float(u1.w & 0xffff0000u);
        }

        #pragma unroll
        for (int o = 8; o <= 32; o <<= 1) {
            dn  += __shfl_xor(dn, o);
            a0.x += __shfl_xor(a0.x, o); a0.y += __shfl_xor(a0.y, o);
            a0.z += __shfl_xor(a0.z, o); a0.w += __shfl_xor(a0.w, o);
            a1.x += __shfl_xor(a1.x, o); a1.y += __shfl_xor(a1.y, o);
            a1.z += __shfl_xor(a1.z, o); a1.w += __shfl_xor(a1.w, o);
            a2.x += __shfl_xor(a2.x, o); a2.y += __shfl_xor(a2.y, o);
            a2.z += __shfl_xor(a2.z, o); a2.w += __shfl_xor(a2.w, o);
            a3.x += __shfl_xor(a3.x, o); a3.y += __shfl_xor(a3.y, o);
            a3.z += __shfl_xor(a3.z, o); a3.w += __shfl_xor(a3.w, o);
        }

        if (grp == 0) {
            const float rd = 1.f / dn;
            const float4* bp = (const float4*)(bias + fl * 16);
            float4 ov[4] = {a0, a1, a2, a3};
            #pragma unroll
            for (int q = 0; q < 4; ++q) {
                const float4 b4 = bp[q];
                float4 o4;
                o4.x = ov[q].x * rd + b4.x; o4.y = ov[q].y * rd + b4.y;
                o4.z = ov[q].z * rd + b4.z; o4.w = ov[q].w * rd + b4.w;
                if (mode == 0) {
                    o4.x = fmaxf(o4.x, 0.f); o4.y = fmaxf(o4.y, 0.f);
                    o4.z = fmaxf(o4.z, 0.f); o4.w = fmaxf(o4.w, 0.f);
                    ushort4 h4, l4;
                    h4.x = f2bf(o4.x); l4.x = f2bf(o4.x - bf2f(h4.x));
                    h4.y = f2bf(o4.y); l4.y = f2bf(o4.y - bf2f(h4.y));
                    h4.z = f2bf(o4.z); l4.z = f2bf(o4.z - bf2f(h4.z));
                    h4.w = f2bf(o4.w); l4.w = f2bf(o4.w - bf2f(h4.w));
                    const size_t base = (size_t)n * FDIM + fl * 16 + q * 4;
                    *(ushort4*)(PHI + base) = h4;
                    *(ushort4*)(PLO + base) = l4;
                } else {
                    *(float4*)(OUTF + (size_t)n * FDIM + fl * 16 + q * 4) = o4;
                }
            }
        }
    }
}

// ---------------- global mean pool (batch sorted) + final linear ----------------
__global__ __launch_bounds__(128) void pool_linear(
    const float* __restrict__ H, const int* __restrict__ batch,
    const float* __restrict__ Wlin, const float* __restrict__ blin,
    float* __restrict__ out)
{
    const int g = blockIdx.x, f = threadIdx.x;
    int a = 0, b = N_NODES;
    while (a < b) { int mid = (a + b) >> 1; if (batch[mid] < g) a = mid + 1; else b = mid; }
    const int lo = a;
    b = N_NODES;
    while (a < b) { int mid = (a + b) >> 1; if (batch[mid] <= g) a = mid + 1; else b = mid; }
    const int hi = a;

    float acc = 0.f;
    for (int n = lo; n < hi; ++n) acc += H[(size_t)n * FDIM + f];
    const float pooled = acc / fmaxf((float)(hi - lo), 1.0f);

    __shared__ float red0[128], red1[128];
    red0[f] = pooled * Wlin[f * 2 + 0];
    red1[f] = pooled * Wlin[f * 2 + 1];
    __syncthreads();
    for (int st = 64; st; st >>= 1) {
        if (f < st) { red0[f] += red0[f + st]; red1[f] += red1[f + st]; }
        __syncthreads();
    }
    if (f == 0) {
        out[g * 2 + 0] = red0[0] + blin[0];
        out[g * 2 + 1] = red1[0] + blin[1];
    }
}

extern "C" void kernel_launch(void* const* d_in, const int* in_sizes, int n_in,
                              void* d_out, int out_size, void* d_ws, size_t ws_size,
                              hipStream_t stream)
{
    const float* x     = (const float*)d_in[0];
    const int*   ei    = (const int*)d_in[1];
    const int*   batch = (const int*)d_in[2];
    const float* W[3]    = {(const float*)d_in[3],  (const float*)d_in[7],  (const float*)d_in[11]};
    const float* avs[3]  = {(const float*)d_in[4],  (const float*)d_in[8],  (const float*)d_in[12]};
    const float* avd[3]  = {(const float*)d_in[5],  (const float*)d_in[9],  (const float*)d_in[13]};
    const float* bias[3] = {(const float*)d_in[6],  (const float*)d_in[10], (const float*)d_in[14]};
    const float* Wlin = (const float*)d_in[15];
    const float* blin = (const float*)d_in[16];
    float* out = (float*)d_out;

    char* w = (char*)d_ws;
    unsigned short* Ahi = (unsigned short*)w; w += (size_t)N_NODES * FDIM * 2;  // 12.8 MB
    unsigned short* Alo = (unsigned short*)w; w += (size_t)N_NODES * FDIM * 2;  // 12.8 MB
    float* hOf = (float*)Ahi;                                                   // overlay
    unsigned short* Hb = (unsigned short*)w; w += (size_t)N_NODES * FDIM * 2;   // 12.8 MB
    float* attn  = (float*)w; w += 2 * 200192;
    int*   off   = (int*)w;   w += 200192;
    int*   cnt   = (int*)w;   w += 200192;
    int*   bsum  = (int*)w;   w += 4096;
    int*   srcs  = (int*)w;   w += (size_t)EN_TOTAL * 4;
    unsigned short* WT = (unsigned short*)w; w += 3 * 2 * FDIM * FDIM * 2;      // 192 KB
    float* asrcN = attn;
    float* adstN = attn + N_NODES;

    // ---- preps ----
    prep_planes<<<1024, 256, 0, stream>>>(x, Ahi, Alo);
    prep_wt<<<3, 256, 0, stream>>>(W[0], W[1], W[2], WT);

    // ---- CSR by destination (topology shared across layers) ----
    hipMemsetAsync(cnt, 0, N_NODES * sizeof(int), stream);
    count_edges<<<(EN_TOTAL + 255) / 256, 256, 0, stream>>>(ei, cnt);
    scan_block<<<SCAN_NB, 256, 0, stream>>>(cnt, off, bsum);
    scan_sums<<<1, 256, 0, stream>>>(bsum);
    add_base<<<SCAN_NB, 256, 0, stream>>>(off, bsum);
    hipMemsetAsync(cnt, 0, N_NODES * sizeof(int), stream);
    scatter_edges<<<(EN_TOTAL + 255) / 256, 256, 0, stream>>>(ei, off, cnt, srcs);

    // ---- 3 GAT layers ----
    for (int l = 0; l < 3; ++l) {
        const unsigned short* WThi = WT + (size_t)l * 2 * FDIM * FDIM;
        const unsigned short* WTlo = WThi + FDIM * FDIM;
        gemm_mfma2<<<GEMM_BLOCKS, 256, 0, stream>>>(Ahi, Alo, WThi, WTlo,
                                                    avs[l], avd[l], Hb, asrcN, adstN);
        gat_aggregate<<<2048, 256, 0, stream>>>(Hb, off, srcs, asrcN, adstN, bias[l],
                                                Ahi, Alo, hOf, (l < 2) ? 0 : 1);
    }

    // ---- mean pool + linear ----
    pool_linear<<<N_GRAPHS, 128, 0, stream>>>(hOf, batch, Wlin, blin, out);
}

// Round 8
// 422.773 us; speedup vs baseline: 1.0165x; 1.0165x over previous
//
#include <hip/hip_runtime.h>
#include <math.h>

#define N_NODES  50000
#define N_EDGES  800000
#define FDIM     128
#define N_GRAPHS 500
#define NEG_SLOPE 0.2f
#define EN_TOTAL (N_EDGES + N_NODES)
#define SCAN_NB ((N_NODES + 255) / 256)   // 196
#define GEMM_TILES ((N_NODES + 15) / 16)  // 3125
#define GEMM_BLOCKS ((GEMM_TILES + 3) / 4)

typedef short bf16x8 __attribute__((ext_vector_type(8)));
typedef float f32x4 __attribute__((ext_vector_type(4)));

static __device__ __forceinline__ float lrelu(float x) {
    return x >= 0.f ? x : NEG_SLOPE * x;
}
static __device__ __forceinline__ unsigned short f2bf(float v) {
    unsigned int u = __float_as_uint(v);
    u += 0x7fffu + ((u >> 16) & 1u);
    return (unsigned short)(u >> 16);
}
static __device__ __forceinline__ float bf2f(unsigned short s) {
    return __uint_as_float(((unsigned int)s) << 16);
}

// ---------------- split X fp32 -> bf16 hi/lo planes ----------------
__global__ __launch_bounds__(256) void prep_planes(
    const float* __restrict__ X, unsigned short* __restrict__ hi,
    unsigned short* __restrict__ lo)
{
    const int total = N_NODES * FDIM / 4;
    for (int i = blockIdx.x * 256 + threadIdx.x; i < total; i += gridDim.x * 256) {
        const float4 v = ((const float4*)X)[i];
        ushort4 h4, l4;
        h4.x = f2bf(v.x); l4.x = f2bf(v.x - bf2f(h4.x));
        h4.y = f2bf(v.y); l4.y = f2bf(v.y - bf2f(h4.y));
        h4.z = f2bf(v.z); l4.z = f2bf(v.z - bf2f(h4.z));
        h4.w = f2bf(v.w); l4.w = f2bf(v.w - bf2f(h4.w));
        ((ushort4*)hi)[i] = h4;
        ((ushort4*)lo)[i] = l4;
    }
}

// ---------------- W (3 layers) -> transposed bf16 hi/lo planes [c][k] ----------
__global__ __launch_bounds__(256) void prep_wt(
    const float* __restrict__ W0, const float* __restrict__ W1,
    const float* __restrict__ W2, unsigned short* __restrict__ WT)
{
    const float* W = (blockIdx.x == 0) ? W0 : (blockIdx.x == 1) ? W1 : W2;
    unsigned short* hi = WT + (size_t)blockIdx.x * 2 * FDIM * FDIM;
    unsigned short* lo = hi + FDIM * FDIM;
    for (int i = threadIdx.x; i < FDIM * FDIM; i += 256) {
        const int k = i >> 7, c = i & 127;
        const float v = W[i];
        const unsigned short h = f2bf(v);
        hi[c * FDIM + k] = h;
        lo[c * FDIM + k] = f2bf(v - bf2f(h));
    }
}

// ---------------- h = X @ W via split-bf16 MFMA, no LDS, 16-row tiles ----------
// Wave = 16-row tile x 128 cols; 782 blocks -> ~3 waves/SIMD for latency hiding.
// B-frags contiguous bf16x8 loads from precomputed W^T planes (L2-hot).
// 3-pass split: ah*bh + al*bh + ah*bl (fp32-accurate).
__global__ __launch_bounds__(256) void gemm_mfma2(
    const unsigned short* __restrict__ Ahi, const unsigned short* __restrict__ Alo,
    const unsigned short* __restrict__ WThi, const unsigned short* __restrict__ WTlo,
    const float* __restrict__ Avs, const float* __restrict__ Avd,
    unsigned short* __restrict__ Hb, float* __restrict__ asrcN, float* __restrict__ adstN)
{
    const int tid = threadIdx.x, wv = tid >> 6, lane = tid & 63;
    const int r16 = lane & 15, g = lane >> 4;
    const int tile = blockIdx.x * 4 + wv;
    const int m0 = tile * 16;
    if (m0 >= N_NODES) return;

    const size_t ra0 = (size_t)min(m0 + r16, N_NODES - 1) * FDIM;

    f32x4 acc[8];
    #pragma unroll
    for (int t = 0; t < 8; ++t) acc[t] = (f32x4){0.f, 0.f, 0.f, 0.f};

    #pragma unroll
    for (int cc = 0; cc < 4; ++cc) {
        const int k0 = cc * 32 + 8 * g;
        const bf16x8 ah = *(const bf16x8*)(Ahi + ra0 + k0);
        const bf16x8 al = *(const bf16x8*)(Alo + ra0 + k0);
        #pragma unroll
        for (int t = 0; t < 8; ++t) {
            const int c = t * 16 + r16;
            const bf16x8 bh = *(const bf16x8*)(WThi + c * FDIM + k0);
            const bf16x8 bl = *(const bf16x8*)(WTlo + c * FDIM + k0);
            acc[t] = __builtin_amdgcn_mfma_f32_16x16x32_bf16(ah, bh, acc[t], 0, 0, 0);
            acc[t] = __builtin_amdgcn_mfma_f32_16x16x32_bf16(al, bh, acc[t], 0, 0, 0);
            acc[t] = __builtin_amdgcn_mfma_f32_16x16x32_bf16(ah, bl, acc[t], 0, 0, 0);
        }
    }

    // epilogue: D map (verified): col = t*16 + r16, row = m0 + 4*g + r
    float ps[4] = {0,0,0,0}, pd[4] = {0,0,0,0};
    const int rowb = m0 + 4 * g;
    #pragma unroll
    for (int t = 0; t < 8; ++t) {
        const float as_v = Avs[t * 16 + r16];
        const float ad_v = Avd[t * 16 + r16];
        #pragma unroll
        for (int r = 0; r < 4; ++r) {
            const float h = acc[t][r];
            if (rowb + r < N_NODES)
                Hb[(size_t)(rowb + r) * FDIM + t * 16 + r16] = f2bf(h);
            ps[r] = fmaf(h, as_v, ps[r]);
            pd[r] = fmaf(h, ad_v, pd[r]);
        }
    }
    #pragma unroll
    for (int o = 1; o <= 8; o <<= 1) {
        #pragma unroll
        for (int r = 0; r < 4; ++r) {
            ps[r] += __shfl_xor(ps[r], o);
            pd[r] += __shfl_xor(pd[r], o);
        }
    }
    if (r16 == 0) {
        #pragma unroll
        for (int r = 0; r < 4; ++r) {
            if (rowb + r < N_NODES) { asrcN[rowb + r] = ps[r]; adstN[rowb + r] = pd[r]; }
        }
    }
}

// ---------------- CSR build ----------------
__global__ void count_edges(const int* __restrict__ ei, int* __restrict__ cnt) {
    int i = blockIdx.x * 256 + threadIdx.x;
    if (i < EN_TOTAL) {
        int d = (i < N_EDGES) ? ei[N_EDGES + i] : (i - N_EDGES);
        atomicAdd(&cnt[d], 1);
    }
}

__global__ __launch_bounds__(256) void scan_block(const int* __restrict__ cnt,
                                                  int* __restrict__ off,
                                                  int* __restrict__ blockSums) {
    __shared__ int s[256];
    const int i = blockIdx.x * 256 + threadIdx.x;
    s[threadIdx.x] = (i < N_NODES) ? cnt[i] : 0;
    __syncthreads();
    #pragma unroll
    for (int d = 1; d < 256; d <<= 1) {
        int t = (threadIdx.x >= d) ? s[threadIdx.x - d] : 0;
        __syncthreads();
        s[threadIdx.x] += t;
        __syncthreads();
    }
    if (i < N_NODES) off[i + 1] = s[threadIdx.x];
    if (threadIdx.x == 255) blockSums[blockIdx.x] = s[255];
}

__global__ __launch_bounds__(256) void scan_sums(int* __restrict__ blockSums) {
    __shared__ int s[256];
    s[threadIdx.x] = (threadIdx.x < SCAN_NB) ? blockSums[threadIdx.x] : 0;
    __syncthreads();
    #pragma unroll
    for (int d = 1; d < 256; d <<= 1) {
        int t = (threadIdx.x >= d) ? s[threadIdx.x - d] : 0;
        __syncthreads();
        s[threadIdx.x] += t;
        __syncthreads();
    }
    if (threadIdx.x < SCAN_NB)
        blockSums[threadIdx.x] = (threadIdx.x == 0) ? 0 : s[threadIdx.x - 1];
}

__global__ __launch_bounds__(256) void add_base(int* __restrict__ off,
                                                const int* __restrict__ blockSums) {
    const int i = blockIdx.x * 256 + threadIdx.x;
    if (i < N_NODES) off[i + 1] += blockSums[blockIdx.x];
    if (i == 0) off[0] = 0;
}

__global__ void scatter_edges(const int* __restrict__ ei, const int* __restrict__ off,
                              int* __restrict__ cur, int* __restrict__ srcs) {
    int i = blockIdx.x * 256 + threadIdx.x;
    if (i < EN_TOTAL) {
        int s, d;
        if (i < N_EDGES) { s = ei[i]; d = ei[N_EDGES + i]; }
        else             { s = d = i - N_EDGES; }
        int p = off[d] + atomicAdd(&cur[d], 1);
        srcs[p] = s;
    }
}

// ---------------- segment softmax + weighted aggregation (bf16 H gather) -------
// R6-proven structure: one wave per dst node; 8 edge-groups x 8 feature-lanes.
__global__ __launch_bounds__(256) void gat_aggregate(
    const unsigned short* __restrict__ Hb, const int* __restrict__ off,
    const int* __restrict__ srcs,
    const float* __restrict__ asrcN, const float* __restrict__ adstN,
    const float* __restrict__ bias,
    unsigned short* __restrict__ PHI, unsigned short* __restrict__ PLO,
    float* __restrict__ OUTF, int mode)
{
    const int wave = threadIdx.x >> 6, lane = threadIdx.x & 63;
    const int grp = lane >> 3, fl = lane & 7;

    for (int n = blockIdx.x * 4 + wave; n < N_NODES; n += gridDim.x * 4) {
        const int s0 = off[n], s1 = off[n + 1];
        const int deg = s1 - s0;
        const float ad = adstN[n];

        float e_reg = -1e30f;
        float m = -1e30f;
        for (int j = s0 + lane; j < s1; j += 64) {
            float e = lrelu(asrcN[srcs[j]] + ad);
            if (j - s0 < 64) e_reg = e;
            m = fmaxf(m, e);
        }
        #pragma unroll
        for (int o = 32; o; o >>= 1) m = fmaxf(m, __shfl_xor(m, o));

        float4 a0 = {0,0,0,0}, a1 = {0,0,0,0}, a2 = {0,0,0,0}, a3 = {0,0,0,0};
        float dn = 0.f;
        const unsigned short* Hf = Hb + (size_t)fl * 16;
        for (int j = s0 + grp; j < s1; j += 8) {
            const int s = srcs[j];
            const float ex = (deg <= 64)
                ? __expf(__shfl(e_reg, j - s0) - m)
                : __expf(lrelu(asrcN[s] + ad) - m);
            dn += ex;
            const uint4* hp = (const uint4*)(Hf + (size_t)s * FDIM);
            const uint4 u0 = hp[0], u1 = hp[1];
            a0.x += ex * __uint_as_float(u0.x << 16);
            a0.y += ex * __uint_as_float(u0.x & 0xffff0000u);
            a0.z += ex * __uint_as_float(u0.y << 16);
            a0.w += ex * __uint_as_float(u0.y & 0xffff0000u);
            a1.x += ex * __uint_as_float(u0.z << 16);
            a1.y += ex * __uint_as_float(u0.z & 0xffff0000u);
            a1.z += ex * __uint_as_float(u0.w << 16);
            a1.w += ex * __uint_as_float(u0.w & 0xffff0000u);
            a2.x += ex * __uint_as_float(u1.x << 16);
            a2.y += ex * __uint_as_float(u1.x & 0xffff0000u);
            a2.z += ex * __uint_as_float(u1.y << 16);
            a2.w += ex * __uint_as_float(u1.y & 0xffff0000u);
            a3.x += ex * __uint_as_float(u1.z << 16);
            a3.y += ex * __uint_as_float(u1.z & 0xffff0000u);
            a3.z += ex * __uint_as_float(u1.w << 16);
            a3.w += ex * __uint_as_float(u1.w & 0xffff0000u);
        }

        #pragma unroll
        for (int o = 8; o <= 32; o <<= 1) {
            dn  += __shfl_xor(dn, o);
            a0.x += __shfl_xor(a0.x, o); a0.y += __shfl_xor(a0.y, o);
            a0.z += __shfl_xor(a0.z, o); a0.w += __shfl_xor(a0.w, o);
            a1.x += __shfl_xor(a1.x, o); a1.y += __shfl_xor(a1.y, o);
            a1.z += __shfl_xor(a1.z, o); a1.w += __shfl_xor(a1.w, o);
            a2.x += __shfl_xor(a2.x, o); a2.y += __shfl_xor(a2.y, o);
            a2.z += __shfl_xor(a2.z, o); a2.w += __shfl_xor(a2.w, o);
            a3.x += __shfl_xor(a3.x, o); a3.y += __shfl_xor(a3.y, o);
            a3.z += __shfl_xor(a3.z, o); a3.w += __shfl_xor(a3.w, o);
        }

        if (grp == 0) {
            const float rd = 1.f / dn;
            const float4* bp = (const float4*)(bias + fl * 16);
            float4 ov[4] = {a0, a1, a2, a3};
            #pragma unroll
            for (int q = 0; q < 4; ++q) {
                const float4 b4 = bp[q];
                float4 o4;
                o4.x = ov[q].x * rd + b4.x; o4.y = ov[q].y * rd + b4.y;
                o4.z = ov[q].z * rd + b4.z; o4.w = ov[q].w * rd + b4.w;
                if (mode == 0) {
                    o4.x = fmaxf(o4.x, 0.f); o4.y = fmaxf(o4.y, 0.f);
                    o4.z = fmaxf(o4.z, 0.f); o4.w = fmaxf(o4.w, 0.f);
                    ushort4 h4, l4;
                    h4.x = f2bf(o4.x); l4.x = f2bf(o4.x - bf2f(h4.x));
                    h4.y = f2bf(o4.y); l4.y = f2bf(o4.y - bf2f(h4.y));
                    h4.z = f2bf(o4.z); l4.z = f2bf(o4.z - bf2f(h4.z));
                    h4.w = f2bf(o4.w); l4.w = f2bf(o4.w - bf2f(h4.w));
                    const size_t base = (size_t)n * FDIM + fl * 16 + q * 4;
                    *(ushort4*)(PHI + base) = h4;
                    *(ushort4*)(PLO + base) = l4;
                } else {
                    *(float4*)(OUTF + (size_t)n * FDIM + fl * 16 + q * 4) = o4;
                }
            }
        }
    }
}

// ---------------- global mean pool (batch sorted) + final linear ----------------
__global__ __launch_bounds__(128) void pool_linear(
    const float* __restrict__ H, const int* __restrict__ batch,
    const float* __restrict__ Wlin, const float* __restrict__ blin,
    float* __restrict__ out)
{
    const int g = blockIdx.x, f = threadIdx.x;
    int a = 0, b = N_NODES;
    while (a < b) { int mid = (a + b) >> 1; if (batch[mid] < g) a = mid + 1; else b = mid; }
    const int lo = a;
    b = N_NODES;
    while (a < b) { int mid = (a + b) >> 1; if (batch[mid] <= g) a = mid + 1; else b = mid; }
    const int hi = a;

    float acc = 0.f;
    for (int n = lo; n < hi; ++n) acc += H[(size_t)n * FDIM + f];
    const float pooled = acc / fmaxf((float)(hi - lo), 1.0f);

    __shared__ float red0[128], red1[128];
    red0[f] = pooled * Wlin[f * 2 + 0];
    red1[f] = pooled * Wlin[f * 2 + 1];
    __syncthreads();
    for (int st = 64; st; st >>= 1) {
        if (f < st) { red0[f] += red0[f + st]; red1[f] += red1[f + st]; }
        __syncthreads();
    }
    if (f == 0) {
        out[g * 2 + 0] = red0[0] + blin[0];
        out[g * 2 + 1] = red1[0] + blin[1];
    }
}

extern "C" void kernel_launch(void* const* d_in, const int* in_sizes, int n_in,
                              void* d_out, int out_size, void* d_ws, size_t ws_size,
                              hipStream_t stream)
{
    const float* x     = (const float*)d_in[0];
    const int*   ei    = (const int*)d_in[1];
    const int*   batch = (const int*)d_in[2];
    const float* W[3]    = {(const float*)d_in[3],  (const float*)d_in[7],  (const float*)d_in[11]};
    const float* avs[3]  = {(const float*)d_in[4],  (const float*)d_in[8],  (const float*)d_in[12]};
    const float* avd[3]  = {(const float*)d_in[5],  (const float*)d_in[9],  (const float*)d_in[13]};
    const float* bias[3] = {(const float*)d_in[6],  (const float*)d_in[10], (const float*)d_in[14]};
    const float* Wlin = (const float*)d_in[15];
    const float* blin = (const float*)d_in[16];
    float* out = (float*)d_out;

    char* w = (char*)d_ws;
    unsigned short* Ahi = (unsigned short*)w; w += (size_t)N_NODES * FDIM * 2;  // 12.8 MB
    unsigned short* Alo = (unsigned short*)w; w += (size_t)N_NODES * FDIM * 2;  // 12.8 MB
    float* hOf = (float*)Ahi;                                                   // overlay
    unsigned short* Hb = (unsigned short*)w; w += (size_t)N_NODES * FDIM * 2;   // 12.8 MB
    float* attn  = (float*)w; w += 2 * 200192;
    int*   off   = (int*)w;   w += 200192;
    int*   cnt   = (int*)w;   w += 200192;
    int*   bsum  = (int*)w;   w += 4096;
    int*   srcs  = (int*)w;   w += (size_t)EN_TOTAL * 4;
    unsigned short* WT = (unsigned short*)w; w += 3 * 2 * FDIM * FDIM * 2;      // 192 KB
    float* asrcN = attn;
    float* adstN = attn + N_NODES;

    // ---- preps ----
    prep_planes<<<1024, 256, 0, stream>>>(x, Ahi, Alo);
    prep_wt<<<3, 256, 0, stream>>>(W[0], W[1], W[2], WT);

    // ---- CSR by destination (topology shared across layers) ----
    hipMemsetAsync(cnt, 0, N_NODES * sizeof(int), stream);
    count_edges<<<(EN_TOTAL + 255) / 256, 256, 0, stream>>>(ei, cnt);
    scan_block<<<SCAN_NB, 256, 0, stream>>>(cnt, off, bsum);
    scan_sums<<<1, 256, 0, stream>>>(bsum);
    add_base<<<SCAN_NB, 256, 0, stream>>>(off, bsum);
    hipMemsetAsync(cnt, 0, N_NODES * sizeof(int), stream);
    scatter_edges<<<(EN_TOTAL + 255) / 256, 256, 0, stream>>>(ei, off, cnt, srcs);

    // ---- 3 GAT layers ----
    for (int l = 0; l < 3; ++l) {
        const unsigned short* WThi = WT + (size_t)l * 2 * FDIM * FDIM;
        const unsigned short* WTlo = WThi + FDIM * FDIM;
        gemm_mfma2<<<GEMM_BLOCKS, 256, 0, stream>>>(Ahi, Alo, WThi, WTlo,
                                                    avs[l], avd[l], Hb, asrcN, adstN);
        gat_aggregate<<<2048, 256, 0, stream>>>(Hb, off, srcs, asrcN, adstN, bias[l],
                                                Ahi, Alo, hOf, (l < 2) ? 0 : 1);
    }

    // ---- mean pool + linear ----
    pool_linear<<<N_GRAPHS, 128, 0, stream>>>(hOf, batch, Wlin, blin, out);
}

// Round 9
// 352.386 us; speedup vs baseline: 1.2195x; 1.1997x over previous
//
#include <hip/hip_runtime.h>
#include <math.h>

#define N_NODES  50000
#define N_EDGES  800000
#define FDIM     128
#define N_GRAPHS 500
#define NEG_SLOPE 0.2f
#define EN_TOTAL (N_EDGES + N_NODES)
#define SCAN_NB ((N_NODES + 255) / 256)   // 196
#define GEMM_TILES (N_NODES / 16)         // 3125 exact

typedef short bf16x8 __attribute__((ext_vector_type(8)));
typedef float f32x4 __attribute__((ext_vector_type(4)));

static __device__ __forceinline__ float lrelu(float x) {
    return x >= 0.f ? x : NEG_SLOPE * x;
}
static __device__ __forceinline__ unsigned short f2bf(float v) {
    unsigned int u = __float_as_uint(v);
    u += 0x7fffu + ((u >> 16) & 1u);
    return (unsigned short)(u >> 16);
}
static __device__ __forceinline__ float bf2f(unsigned short s) {
    return __uint_as_float(((unsigned int)s) << 16);
}

// ---------------- split X fp32 -> bf16 hi/lo planes ----------------
__global__ __launch_bounds__(256) void prep_planes(
    const float* __restrict__ X, unsigned short* __restrict__ hi,
    unsigned short* __restrict__ lo)
{
    const int total = N_NODES * FDIM / 4;
    for (int i = blockIdx.x * 256 + threadIdx.x; i < total; i += gridDim.x * 256) {
        const float4 v = ((const float4*)X)[i];
        ushort4 h4, l4;
        h4.x = f2bf(v.x); l4.x = f2bf(v.x - bf2f(h4.x));
        h4.y = f2bf(v.y); l4.y = f2bf(v.y - bf2f(h4.y));
        h4.z = f2bf(v.z); l4.z = f2bf(v.z - bf2f(h4.z));
        h4.w = f2bf(v.w); l4.w = f2bf(v.w - bf2f(h4.w));
        ((ushort4*)hi)[i] = h4;
        ((ushort4*)lo)[i] = l4;
    }
}

// ---------------- W (3 layers) -> transposed bf16 hi/lo planes [c][k] ----------
__global__ __launch_bounds__(256) void prep_wt(
    const float* __restrict__ W0, const float* __restrict__ W1,
    const float* __restrict__ W2, unsigned short* __restrict__ WT)
{
    const float* W = (blockIdx.x == 0) ? W0 : (blockIdx.x == 1) ? W1 : W2;
    unsigned short* hi = WT + (size_t)blockIdx.x * 2 * FDIM * FDIM;
    unsigned short* lo = hi + FDIM * FDIM;
    for (int i = threadIdx.x; i < FDIM * FDIM; i += 256) {
        const int k = i >> 7, c = i & 127;
        const float v = W[i];
        const unsigned short h = f2bf(v);
        hi[c * FDIM + k] = h;
        lo[c * FDIM + k] = f2bf(v - bf2f(h));
    }
}

// ---------------- h = X @ W, persistent-B split-bf16 MFMA ----------------
// 4 waves/block; wave wv owns cols [32wv, 32wv+32) -> B frags (16 bf16x8 = 64
// VGPR) loaded ONCE, reused across a grid-stride loop over 16-row tiles.
// Per tile/wave: 8 A-loads + 24 MFMA. asrc/adst cross-wave combine via LDS
// (no atomics, no memsets). D map (verified): col=t*16+r16, row=m0+4g+r.
__global__ __launch_bounds__(256) void gemm_mfma3(
    const unsigned short* __restrict__ Ahi, const unsigned short* __restrict__ Alo,
    const unsigned short* __restrict__ WThi, const unsigned short* __restrict__ WTlo,
    const float* __restrict__ Avs, const float* __restrict__ Avd,
    unsigned short* __restrict__ Hb, float* __restrict__ asrcN, float* __restrict__ adstN)
{
    __shared__ float sps[4][16], spd[4][16];

    const int tid = threadIdx.x, wv = tid >> 6, lane = tid & 63;
    const int r16 = lane & 15, g = lane >> 4;
    const int t0 = wv * 2;

    // persistent B fragments + attention coefficients for my 2 col-tiles
    bf16x8 bh[2][4], bl[2][4];
    float as_v[2], ad_v[2];
    #pragma unroll
    for (int tt = 0; tt < 2; ++tt) {
        const int c = (t0 + tt) * 16 + r16;
        as_v[tt] = Avs[c];
        ad_v[tt] = Avd[c];
        #pragma unroll
        for (int cc = 0; cc < 4; ++cc) {
            bh[tt][cc] = *(const bf16x8*)(WThi + c * FDIM + cc * 32 + 8 * g);
            bl[tt][cc] = *(const bf16x8*)(WTlo + c * FDIM + cc * 32 + 8 * g);
        }
    }

    for (int tile = blockIdx.x; tile < GEMM_TILES; tile += gridDim.x) {
        const int m0 = tile * 16;
        const size_t ra = (size_t)(m0 + r16) * FDIM;

        f32x4 acc0 = {0.f, 0.f, 0.f, 0.f}, acc1 = {0.f, 0.f, 0.f, 0.f};
        #pragma unroll
        for (int cc = 0; cc < 4; ++cc) {
            const int k0 = cc * 32 + 8 * g;
            const bf16x8 ah = *(const bf16x8*)(Ahi + ra + k0);
            const bf16x8 al = *(const bf16x8*)(Alo + ra + k0);
            acc0 = __builtin_amdgcn_mfma_f32_16x16x32_bf16(ah, bh[0][cc], acc0, 0, 0, 0);
            acc1 = __builtin_amdgcn_mfma_f32_16x16x32_bf16(ah, bh[1][cc], acc1, 0, 0, 0);
            acc0 = __builtin_amdgcn_mfma_f32_16x16x32_bf16(al, bh[0][cc], acc0, 0, 0, 0);
            acc1 = __builtin_amdgcn_mfma_f32_16x16x32_bf16(al, bh[1][cc], acc1, 0, 0, 0);
            acc0 = __builtin_amdgcn_mfma_f32_16x16x32_bf16(ah, bl[0][cc], acc0, 0, 0, 0);
            acc1 = __builtin_amdgcn_mfma_f32_16x16x32_bf16(ah, bl[1][cc], acc1, 0, 0, 0);
        }

        // H store + per-wave partial attention dots
        float ps[4], pd[4];
        const int rowb = m0 + 4 * g;
        #pragma unroll
        for (int r = 0; r < 4; ++r) {
            const float h0 = acc0[r], h1 = acc1[r];
            Hb[(size_t)(rowb + r) * FDIM + (t0 + 0) * 16 + r16] = f2bf(h0);
            Hb[(size_t)(rowb + r) * FDIM + (t0 + 1) * 16 + r16] = f2bf(h1);
            ps[r] = h0 * as_v[0] + h1 * as_v[1];
            pd[r] = h0 * ad_v[0] + h1 * ad_v[1];
        }
        #pragma unroll
        for (int o = 1; o <= 8; o <<= 1) {
            #pragma unroll
            for (int r = 0; r < 4; ++r) {
                ps[r] += __shfl_xor(ps[r], o);
                pd[r] += __shfl_xor(pd[r], o);
            }
        }
        if (r16 == 0) {
            #pragma unroll
            for (int r = 0; r < 4; ++r) {
                sps[wv][4 * g + r] = ps[r];
                spd[wv][4 * g + r] = pd[r];
            }
        }
        __syncthreads();
        if (tid < 16) {
            asrcN[m0 + tid] = sps[0][tid] + sps[1][tid] + sps[2][tid] + sps[3][tid];
        } else if (tid < 32) {
            const int r = tid - 16;
            adstN[m0 + r] = spd[0][r] + spd[1][r] + spd[2][r] + spd[3][r];
        }
        __syncthreads();
    }
}

// ---------------- CSR build ----------------
__global__ void count_edges(const int* __restrict__ ei, int* __restrict__ cnt) {
    int i = blockIdx.x * 256 + threadIdx.x;
    if (i < EN_TOTAL) {
        int d = (i < N_EDGES) ? ei[N_EDGES + i] : (i - N_EDGES);
        atomicAdd(&cnt[d], 1);
    }
}

__global__ __launch_bounds__(256) void scan_block(const int* __restrict__ cnt,
                                                  int* __restrict__ off,
                                                  int* __restrict__ blockSums) {
    __shared__ int s[256];
    const int i = blockIdx.x * 256 + threadIdx.x;
    s[threadIdx.x] = (i < N_NODES) ? cnt[i] : 0;
    __syncthreads();
    #pragma unroll
    for (int d = 1; d < 256; d <<= 1) {
        int t = (threadIdx.x >= d) ? s[threadIdx.x - d] : 0;
        __syncthreads();
        s[threadIdx.x] += t;
        __syncthreads();
    }
    if (i < N_NODES) off[i + 1] = s[threadIdx.x];
    if (threadIdx.x == 255) blockSums[blockIdx.x] = s[255];
}

__global__ __launch_bounds__(256) void scan_sums(int* __restrict__ blockSums) {
    __shared__ int s[256];
    s[threadIdx.x] = (threadIdx.x < SCAN_NB) ? blockSums[threadIdx.x] : 0;
    __syncthreads();
    #pragma unroll
    for (int d = 1; d < 256; d <<= 1) {
        int t = (threadIdx.x >= d) ? s[threadIdx.x - d] : 0;
        __syncthreads();
        s[threadIdx.x] += t;
        __syncthreads();
    }
    if (threadIdx.x < SCAN_NB)
        blockSums[threadIdx.x] = (threadIdx.x == 0) ? 0 : s[threadIdx.x - 1];
}

__global__ __launch_bounds__(256) void add_base(int* __restrict__ off,
                                                const int* __restrict__ blockSums) {
    const int i = blockIdx.x * 256 + threadIdx.x;
    if (i < N_NODES) off[i + 1] += blockSums[blockIdx.x];
    if (i == 0) off[0] = 0;
}

__global__ void scatter_edges(const int* __restrict__ ei, const int* __restrict__ off,
                              int* __restrict__ cur, int* __restrict__ srcs) {
    int i = blockIdx.x * 256 + threadIdx.x;
    if (i < EN_TOTAL) {
        int s, d;
        if (i < N_EDGES) { s = ei[i]; d = ei[N_EDGES + i]; }
        else             { s = d = i - N_EDGES; }
        int p = off[d] + atomicAdd(&cur[d], 1);
        srcs[p] = s;
    }
}

// ---------------- segment softmax + weighted aggregation (bf16 H gather) -------
// R6-proven structure: one wave per dst node; 8 edge-groups x 8 feature-lanes.
__global__ __launch_bounds__(256) void gat_aggregate(
    const unsigned short* __restrict__ Hb, const int* __restrict__ off,
    const int* __restrict__ srcs,
    const float* __restrict__ asrcN, const float* __restrict__ adstN,
    const float* __restrict__ bias,
    unsigned short* __restrict__ PHI, unsigned short* __restrict__ PLO,
    float* __restrict__ OUTF, int mode)
{
    const int wave = threadIdx.x >> 6, lane = threadIdx.x & 63;
    const int grp = lane >> 3, fl = lane & 7;

    for (int n = blockIdx.x * 4 + wave; n < N_NODES; n += gridDim.x * 4) {
        const int s0 = off[n], s1 = off[n + 1];
        const int deg = s1 - s0;
        const float ad = adstN[n];

        float e_reg = -1e30f;
        float m = -1e30f;
        for (int j = s0 + lane; j < s1; j += 64) {
            float e = lrelu(asrcN[srcs[j]] + ad);
            if (j - s0 < 64) e_reg = e;
            m = fmaxf(m, e);
        }
        #pragma unroll
        for (int o = 32; o; o >>= 1) m = fmaxf(m, __shfl_xor(m, o));

        float4 a0 = {0,0,0,0}, a1 = {0,0,0,0}, a2 = {0,0,0,0}, a3 = {0,0,0,0};
        float dn = 0.f;
        const unsigned short* Hf = Hb + (size_t)fl * 16;
        for (int j = s0 + grp; j < s1; j += 8) {
            const int s = srcs[j];
            const float ex = (deg <= 64)
                ? __expf(__shfl(e_reg, j - s0) - m)
                : __expf(lrelu(asrcN[s] + ad) - m);
            dn += ex;
            const uint4* hp = (const uint4*)(Hf + (size_t)s * FDIM);
            const uint4 u0 = hp[0], u1 = hp[1];
            a0.x += ex * __uint_as_float(u0.x << 16);
            a0.y += ex * __uint_as_float(u0.x & 0xffff0000u);
            a0.z += ex * __uint_as_float(u0.y << 16);
            a0.w += ex * __uint_as_float(u0.y & 0xffff0000u);
            a1.x += ex * __uint_as_float(u0.z << 16);
            a1.y += ex * __uint_as_float(u0.z & 0xffff0000u);
            a1.z += ex * __uint_as_float(u0.w << 16);
            a1.w += ex * __uint_as_float(u0.w & 0xffff0000u);
            a2.x += ex * __uint_as_float(u1.x << 16);
            a2.y += ex * __uint_as_float(u1.x & 0xffff0000u);
            a2.z += ex * __uint_as_float(u1.y << 16);
            a2.w += ex * __uint_as_float(u1.y & 0xffff0000u);
            a3.x += ex * __uint_as_float(u1.z << 16);
            a3.y += ex * __uint_as_float(u1.z & 0xffff0000u);
            a3.z += ex * __uint_as_float(u1.w << 16);
            a3.w += ex * __uint_as_float(u1.w & 0xffff0000u);
        }

        #pragma unroll
        for (int o = 8; o <= 32; o <<= 1) {
            dn  += __shfl_xor(dn, o);
            a0.x += __shfl_xor(a0.x, o); a0.y += __shfl_xor(a0.y, o);
            a0.z += __shfl_xor(a0.z, o); a0.w += __shfl_xor(a0.w, o);
            a1.x += __shfl_xor(a1.x, o); a1.y += __shfl_xor(a1.y, o);
            a1.z += __shfl_xor(a1.z, o); a1.w += __shfl_xor(a1.w, o);
            a2.x += __shfl_xor(a2.x, o); a2.y += __shfl_xor(a2.y, o);
            a2.z += __shfl_xor(a2.z, o); a2.w += __shfl_xor(a2.w, o);
            a3.x += __shfl_xor(a3.x, o); a3.y += __shfl_xor(a3.y, o);
            a3.z += __shfl_xor(a3.z, o); a3.w += __shfl_xor(a3.w, o);
        }

        if (grp == 0) {
            const float rd = 1.f / dn;
            const float4* bp = (const float4*)(bias + fl * 16);
            float4 ov[4] = {a0, a1, a2, a3};
            #pragma unroll
            for (int q = 0; q < 4; ++q) {
                const float4 b4 = bp[q];
                float4 o4;
                o4.x = ov[q].x * rd + b4.x; o4.y = ov[q].y * rd + b4.y;
                o4.z = ov[q].z * rd + b4.z; o4.w = ov[q].w * rd + b4.w;
                if (mode == 0) {
                    o4.x = fmaxf(o4.x, 0.f); o4.y = fmaxf(o4.y, 0.f);
                    o4.z = fmaxf(o4.z, 0.f); o4.w = fmaxf(o4.w, 0.f);
                    ushort4 h4, l4;
                    h4.x = f2bf(o4.x); l4.x = f2bf(o4.x - bf2f(h4.x));
                    h4.y = f2bf(o4.y); l4.y = f2bf(o4.y - bf2f(h4.y));
                    h4.z = f2bf(o4.z); l4.z = f2bf(o4.z - bf2f(h4.z));
                    h4.w = f2bf(o4.w); l4.w = f2bf(o4.w - bf2f(h4.w));
                    const size_t base = (size_t)n * FDIM + fl * 16 + q * 4;
                    *(ushort4*)(PHI + base) = h4;
                    *(ushort4*)(PLO + base) = l4;
                } else {
                    *(float4*)(OUTF + (size_t)n * FDIM + fl * 16 + q * 4) = o4;
                }
            }
        }
    }
}

// ---------------- global mean pool + final linear (8 rows in flight) ----------
__global__ __launch_bounds__(256) void pool_linear2(
    const float* __restrict__ H, const int* __restrict__ batch,
    const float* __restrict__ Wlin, const float* __restrict__ blin,
    float* __restrict__ out)
{
    const int g = blockIdx.x, tid = threadIdx.x;
    const int rl = tid >> 5, fq = tid & 31;

    int a = 0, b = N_NODES;
    while (a < b) { int mid = (a + b) >> 1; if (batch[mid] < g) a = mid + 1; else b = mid; }
    const int lo = a;
    b = N_NODES;
    while (a < b) { int mid = (a + b) >> 1; if (batch[mid] <= g) a = mid + 1; else b = mid; }
    const int hi = a;

    float4 acc = {0.f, 0.f, 0.f, 0.f};
    for (int n = lo + rl; n < hi; n += 8) {
        const float4 v = *(const float4*)(H + (size_t)n * FDIM + fq * 4);
        acc.x += v.x; acc.y += v.y; acc.z += v.z; acc.w += v.w;
    }
    __shared__ float4 s[8][32];
    s[rl][fq] = acc;
    __syncthreads();

    if (tid < 32) {
        float4 t = s[0][fq];
        #pragma unroll
        for (int r = 1; r < 8; ++r) {
            const float4 v = s[r][fq];
            t.x += v.x; t.y += v.y; t.z += v.z; t.w += v.w;
        }
        const float inv = 1.f / fmaxf((float)(hi - lo), 1.f);
        t.x *= inv; t.y *= inv; t.z *= inv; t.w *= inv;
        float d0 = t.x * Wlin[(fq * 4 + 0) * 2 + 0] + t.y * Wlin[(fq * 4 + 1) * 2 + 0]
                 + t.z * Wlin[(fq * 4 + 2) * 2 + 0] + t.w * Wlin[(fq * 4 + 3) * 2 + 0];
        float d1 = t.x * Wlin[(fq * 4 + 0) * 2 + 1] + t.y * Wlin[(fq * 4 + 1) * 2 + 1]
                 + t.z * Wlin[(fq * 4 + 2) * 2 + 1] + t.w * Wlin[(fq * 4 + 3) * 2 + 1];
        #pragma unroll
        for (int o = 1; o <= 16; o <<= 1) {
            d0 += __shfl_xor(d0, o);
            d1 += __shfl_xor(d1, o);
        }
        if (fq == 0) {
            out[g * 2 + 0] = d0 + blin[0];
            out[g * 2 + 1] = d1 + blin[1];
        }
    }
}

extern "C" void kernel_launch(void* const* d_in, const int* in_sizes, int n_in,
                              void* d_out, int out_size, void* d_ws, size_t ws_size,
                              hipStream_t stream)
{
    const float* x     = (const float*)d_in[0];
    const int*   ei    = (const int*)d_in[1];
    const int*   batch = (const int*)d_in[2];
    const float* W[3]    = {(const float*)d_in[3],  (const float*)d_in[7],  (const float*)d_in[11]};
    const float* avs[3]  = {(const float*)d_in[4],  (const float*)d_in[8],  (const float*)d_in[12]};
    const float* avd[3]  = {(const float*)d_in[5],  (const float*)d_in[9],  (const float*)d_in[13]};
    const float* bias[3] = {(const float*)d_in[6],  (const float*)d_in[10], (const float*)d_in[14]};
    const float* Wlin = (const float*)d_in[15];
    const float* blin = (const float*)d_in[16];
    float* out = (float*)d_out;

    char* w = (char*)d_ws;
    unsigned short* Ahi = (unsigned short*)w; w += (size_t)N_NODES * FDIM * 2;  // 12.8 MB
    unsigned short* Alo = (unsigned short*)w; w += (size_t)N_NODES * FDIM * 2;  // 12.8 MB
    float* hOf = (float*)Ahi;                                                   // overlay
    unsigned short* Hb = (unsigned short*)w; w += (size_t)N_NODES * FDIM * 2;   // 12.8 MB
    float* attn  = (float*)w; w += 2 * 200192;
    int*   off   = (int*)w;   w += 200192;
    int*   cnt   = (int*)w;   w += 200192;
    int*   bsum  = (int*)w;   w += 4096;
    int*   srcs  = (int*)w;   w += (size_t)EN_TOTAL * 4;
    unsigned short* WT = (unsigned short*)w; w += 3 * 2 * FDIM * FDIM * 2;      // 192 KB
    float* asrcN = attn;
    float* adstN = attn + N_NODES;

    // ---- preps ----
    prep_planes<<<1024, 256, 0, stream>>>(x, Ahi, Alo);
    prep_wt<<<3, 256, 0, stream>>>(W[0], W[1], W[2], WT);

    // ---- CSR by destination (topology shared across layers) ----
    hipMemsetAsync(cnt, 0, N_NODES * sizeof(int), stream);
    count_edges<<<(EN_TOTAL + 255) / 256, 256, 0, stream>>>(ei, cnt);
    scan_block<<<SCAN_NB, 256, 0, stream>>>(cnt, off, bsum);
    scan_sums<<<1, 256, 0, stream>>>(bsum);
    add_base<<<SCAN_NB, 256, 0, stream>>>(off, bsum);
    hipMemsetAsync(cnt, 0, N_NODES * sizeof(int), stream);
    scatter_edges<<<(EN_TOTAL + 255) / 256, 256, 0, stream>>>(ei, off, cnt, srcs);

    // ---- 3 GAT layers ----
    for (int l = 0; l < 3; ++l) {
        const unsigned short* WThi = WT + (size_t)l * 2 * FDIM * FDIM;
        const unsigned short* WTlo = WThi + FDIM * FDIM;
        gemm_mfma3<<<1024, 256, 0, stream>>>(Ahi, Alo, WThi, WTlo,
                                             avs[l], avd[l], Hb, asrcN, adstN);
        gat_aggregate<<<2048, 256, 0, stream>>>(Hb, off, srcs, asrcN, adstN, bias[l],
                                                Ahi, Alo, hOf, (l < 2) ? 0 : 1);
    }

    // ---- mean pool + linear ----
    pool_linear2<<<N_GRAPHS, 256, 0, stream>>>(hOf, batch, Wlin, blin, out);
}